// Round 1
// baseline (984.835 us; speedup 1.0000x reference)
//
#include <hip/hip_runtime.h>
#include <cstdint>

#define S_FRAMES 64
#define NPF      147456           // 384*384
#define TOT      (S_FRAMES * NPF) // 9437184
#define NBINS    16384
#define R0       73727u
#define R1       73728u

// workspace layout (bytes)
#define OFF_HIST 0
#define SZ_HIST  (S_FRAMES * NBINS * 4)   // 4194304
#define OFF_MED  SZ_HIST                  // 4194304 (64 floats)
#define OFF_BBOX (OFF_MED + 256)          // 4194560 (6 u32: min xyz, max xyz encoded)
#define OFF_SUMS (OFF_BBOX + 64)          // 4194624 (2 doubles + 1 ull), 8-aligned
#define OFF_BM   (OFF_SUMS + 64)          // 4194688
#define WORDS_BM 9344                     // 8192 (dim64) + 1024 (dim32) + 128 (dim16)
#define SZ_BM    (S_FRAMES * WORDS_BM * 4)
#define WS_USED  (OFF_BM + SZ_BM)         // ~6.6 MB

__device__ __forceinline__ uint32_t encf(float f) {
    uint32_t u = __float_as_uint(f);
    return (u & 0x80000000u) ? ~u : (u | 0x80000000u);
}
__device__ __forceinline__ float decf(uint32_t e) {
    uint32_t u = (e & 0x80000000u) ? (e & 0x7FFFFFFFu) : ~e;
    return __uint_as_float(u);
}
__device__ __forceinline__ int conf_bin(float v) {
    int b = (int)(v * (float)NBINS);
    return b < 0 ? 0 : (b > NBINS - 1 ? NBINS - 1 : b);
}

// K1a: per-frame conf histogram, 4 blocks/frame
__global__ __launch_bounds__(256) void k_hist(const float* __restrict__ conf,
                                              uint32_t* __restrict__ hist) {
    int f = blockIdx.x >> 2;
    int chunk = blockIdx.x & 3;
    __shared__ uint32_t h[NBINS]; // 64 KB
    for (int i = threadIdx.x; i < NBINS; i += 256) h[i] = 0;
    __syncthreads();
    const float* c = conf + (size_t)f * NPF + (size_t)chunk * (NPF / 4);
    for (int i = threadIdx.x; i < NPF / 4; i += 256)
        atomicAdd(&h[conf_bin(c[i])], 1u);
    __syncthreads();
    uint32_t* gh = hist + (size_t)f * NBINS;
    for (int i = threadIdx.x; i < NBINS; i += 256)
        if (h[i]) atomicAdd(&gh[i], h[i]);
}

// K1b: exact median (ranks R0,R1) per frame from histogram + candidate re-scan
__global__ __launch_bounds__(256) void k_median(const float* __restrict__ conf,
                                                const uint32_t* __restrict__ hist,
                                                float* __restrict__ med) {
    int f = blockIdx.x;
    const uint32_t* gh = hist + (size_t)f * NBINS;
    __shared__ uint32_t part[256];
    __shared__ uint32_t excl[256];
    __shared__ int bin0, bin1;
    __shared__ uint32_t cb0, cb1;
    const int base = threadIdx.x * (NBINS / 256);
    uint32_t s = 0;
    for (int j = 0; j < NBINS / 256; j++) s += gh[base + j];
    part[threadIdx.x] = s;
    __syncthreads();
    if (threadIdx.x == 0) {
        uint32_t run = 0;
        for (int t = 0; t < 256; t++) { excl[t] = run; run += part[t]; }
    }
    __syncthreads();
    uint32_t e = excl[threadIdx.x], p = part[threadIdx.x];
    if (R0 >= e && R0 < e + p) {
        uint32_t cum = e;
        for (int j = 0; j < NBINS / 256; j++) {
            uint32_t c2 = gh[base + j];
            if (R0 < cum + c2) { bin0 = base + j; cb0 = cum; break; }
            cum += c2;
        }
    }
    if (R1 >= e && R1 < e + p) {
        uint32_t cum = e;
        for (int j = 0; j < NBINS / 256; j++) {
            uint32_t c2 = gh[base + j];
            if (R1 < cum + c2) { bin1 = base + j; cb1 = cum; break; }
            cum += c2;
        }
    }
    __syncthreads();
    const int CAP = 1024;
    __shared__ float buf0[CAP], buf1[CAP];
    __shared__ uint32_t n0, n1;
    if (threadIdx.x == 0) { n0 = 0; n1 = 0; }
    __syncthreads();
    int b0 = bin0, b1 = bin1;
    const float* c = conf + (size_t)f * NPF;
    for (int i = threadIdx.x; i < NPF; i += 256) {
        float v = c[i];
        int b = conf_bin(v);
        if (b == b0) {
            uint32_t k = atomicAdd(&n0, 1u); if (k < CAP) buf0[k] = v;
        } else if (b == b1) {
            uint32_t k = atomicAdd(&n1, 1u); if (k < CAP) buf1[k] = v;
        }
    }
    __syncthreads();
    if (threadIdx.x == 0) {
        int m0 = (int)(n0 < CAP ? n0 : CAP);
        for (int i = 1; i < m0; i++) {
            float key = buf0[i]; int j = i - 1;
            while (j >= 0 && buf0[j] > key) { buf0[j + 1] = buf0[j]; j--; }
            buf0[j + 1] = key;
        }
        float v0 = buf0[R0 - cb0];
        float v1;
        if (b1 == b0) {
            v1 = buf0[R1 - cb0];
        } else {
            int m1 = (int)(n1 < CAP ? n1 : CAP);
            for (int i = 1; i < m1; i++) {
                float key = buf1[i]; int j = i - 1;
                while (j >= 0 && buf1[j] > key) { buf1[j + 1] = buf1[j]; j--; }
                buf1[j + 1] = key;
            }
            v1 = buf1[R1 - cb1];
        }
        med[f] = 0.5f * v0 + 0.5f * v1;
    }
}

// K2: fused bbox (valid pts) + complexity sums (mask pts)
__global__ __launch_bounds__(256) void k_stats(const float* __restrict__ pts,
                                               const float* __restrict__ conf,
                                               const float* __restrict__ med,
                                               uint32_t* __restrict__ bbox,
                                               double* __restrict__ sums) {
    int tid = blockIdx.x * blockDim.x + threadIdx.x;
    int stride = gridDim.x * blockDim.x;
    float mnx = 1e30f, mny = 1e30f, mnz = 1e30f;
    float mxx = -1e30f, mxy = -1e30f, mxz = -1e30f;
    double s1 = 0.0, s2 = 0.0;
    uint32_t cnt = 0;
    for (int i = tid; i < TOT; i += stride) {
        float c = conf[i];
        size_t b3 = 3 * (size_t)i;
        float x = pts[b3], y = pts[b3 + 1], z = pts[b3 + 2];
        if (c > 0.1f) {
            float d = sqrtf(x * x + y * y + z * z);
            s1 += (double)d;
            s2 += (double)d * (double)d;
            cnt++;
            int f = i / NPF;
            if (c >= med[f]) {
                mnx = fminf(mnx, x); mny = fminf(mny, y); mnz = fminf(mnz, z);
                mxx = fmaxf(mxx, x); mxy = fmaxf(mxy, y); mxz = fmaxf(mxz, z);
            }
        }
    }
    for (int o = 32; o > 0; o >>= 1) {
        mnx = fminf(mnx, __shfl_xor(mnx, o)); mny = fminf(mny, __shfl_xor(mny, o));
        mnz = fminf(mnz, __shfl_xor(mnz, o));
        mxx = fmaxf(mxx, __shfl_xor(mxx, o)); mxy = fmaxf(mxy, __shfl_xor(mxy, o));
        mxz = fmaxf(mxz, __shfl_xor(mxz, o));
        s1 += __shfl_xor(s1, o); s2 += __shfl_xor(s2, o);
        cnt += __shfl_xor(cnt, o);
    }
    if ((threadIdx.x & 63) == 0) {
        atomicMin(&bbox[0], encf(mnx)); atomicMin(&bbox[1], encf(mny));
        atomicMin(&bbox[2], encf(mnz));
        atomicMax(&bbox[3], encf(mxx)); atomicMax(&bbox[4], encf(mxy));
        atomicMax(&bbox[5], encf(mxz));
        atomicAdd(&sums[0], s1);
        atomicAdd(&sums[1], s2);
        atomicAdd((unsigned long long*)(sums + 2), (unsigned long long)cnt);
    }
}

// K3: fused 3-scale LDS voxel bitmaps, 4 blocks/frame, OR-merge to global
__global__ __launch_bounds__(256) void k_voxel(const float* __restrict__ pts,
                                               const float* __restrict__ conf,
                                               const float* __restrict__ med,
                                               const uint32_t* __restrict__ bbox,
                                               uint32_t* __restrict__ gbm) {
    int f = blockIdx.x >> 2;
    int chunk = blockIdx.x & 3;
    __shared__ uint32_t bm[WORDS_BM]; // [0,8192)=λ40 dim64, [8192,9216)=λ20 dim32, [9216,9344)=λ10 dim16
    for (int i = threadIdx.x; i < WORDS_BM; i += 256) bm[i] = 0;
    float pmnx = decf(bbox[0]), pmny = decf(bbox[1]), pmnz = decf(bbox[2]);
    float ex = decf(bbox[3]) - pmnx, ey = decf(bbox[4]) - pmny, ez = decf(bbox[5]) - pmnz;
    float me = fminf(ex, fminf(ey, ez));
    float vs40 = me / 40.0f, vs20 = me / 20.0f, vs10 = me / 10.0f;
    float q = med[f];
    __syncthreads();
    const size_t base = (size_t)f * NPF + (size_t)chunk * (NPF / 4);
    for (int i = threadIdx.x; i < NPF / 4; i += 256) {
        size_t gi = base + i;
        float c = conf[gi];
        if (c > 0.1f && c >= q) {
            size_t b3 = 3 * gi;
            float x = pts[b3] - pmnx, y = pts[b3 + 1] - pmny, z = pts[b3 + 2] - pmnz;
            int cx, cy, cz, bit;
            // λ=40, dim 64
            cx = (int)floorf(x / vs40); cy = (int)floorf(y / vs40); cz = (int)floorf(z / vs40);
            cx = min(max(cx, 0), 63); cy = min(max(cy, 0), 63); cz = min(max(cz, 0), 63);
            bit = (cx << 12) | (cy << 6) | cz;
            atomicOr(&bm[bit >> 5], 1u << (bit & 31));
            // λ=20, dim 32
            cx = (int)floorf(x / vs20); cy = (int)floorf(y / vs20); cz = (int)floorf(z / vs20);
            cx = min(max(cx, 0), 31); cy = min(max(cy, 0), 31); cz = min(max(cz, 0), 31);
            bit = (cx << 10) | (cy << 5) | cz;
            atomicOr(&bm[8192 + (bit >> 5)], 1u << (bit & 31));
            // λ=10, dim 16
            cx = (int)floorf(x / vs10); cy = (int)floorf(y / vs10); cz = (int)floorf(z / vs10);
            cx = min(max(cx, 0), 15); cy = min(max(cy, 0), 15); cz = min(max(cz, 0), 15);
            bit = (cx << 8) | (cy << 4) | cz;
            atomicOr(&bm[9216 + (bit >> 5)], 1u << (bit & 31));
        }
    }
    __syncthreads();
    uint32_t* g = gbm + (size_t)f * WORDS_BM;
    for (int i = threadIdx.x; i < WORDS_BM; i += 256) {
        uint32_t v = bm[i];
        if (v) atomicOr(&g[i], v);
    }
}

// K4: popcount per frame -> counts; block 0 finalizes complexity
__global__ __launch_bounds__(256) void k_final(const uint32_t* __restrict__ gbm,
                                               const double* __restrict__ sums,
                                               float* __restrict__ out) {
    int f = blockIdx.x;
    const uint32_t* g = gbm + (size_t)f * WORDS_BM;
    uint32_t c40 = 0, c20 = 0, c10 = 0;
    for (int i = threadIdx.x; i < 8192; i += 256) c40 += __popc(g[i]);
    for (int i = threadIdx.x; i < 1024; i += 256) c20 += __popc(g[8192 + i]);
    for (int i = threadIdx.x; i < 128; i += 256) c10 += __popc(g[9216 + i]);
    for (int o = 32; o > 0; o >>= 1) {
        c40 += __shfl_xor(c40, o);
        c20 += __shfl_xor(c20, o);
        c10 += __shfl_xor(c10, o);
    }
    __shared__ uint32_t red[3][4];
    int wave = threadIdx.x >> 6, lane = threadIdx.x & 63;
    if (lane == 0) { red[0][wave] = c40; red[1][wave] = c20; red[2][wave] = c10; }
    __syncthreads();
    if (threadIdx.x == 0) {
        uint32_t t40 = red[0][0] + red[0][1] + red[0][2] + red[0][3];
        uint32_t t20 = red[1][0] + red[1][1] + red[1][2] + red[1][3];
        uint32_t t10 = red[2][0] + red[2][1] + red[2][2] + red[2][3];
        out[0 * S_FRAMES + f] = (float)t10;
        out[1 * S_FRAMES + f] = (float)t20;
        out[2 * S_FRAMES + f] = (float)t40;
        out[3 * S_FRAMES + f] = (float)t20; // adaptive lambda == 20
        if (f == 0) {
            double n = (double)*(const unsigned long long*)(sums + 2);
            double s1 = sums[0], s2 = sums[1];
            double mean = s1 / n;
            double var = (s2 - n * mean * mean) / (n - 1.0);
            out[4 * S_FRAMES] = (float)(sqrt(var) * (n / (double)TOT));
        }
    }
}

extern "C" void kernel_launch(void* const* d_in, const int* in_sizes, int n_in,
                              void* d_out, int out_size, void* d_ws, size_t ws_size,
                              hipStream_t stream) {
    const float* pts  = (const float*)d_in[0];
    const float* conf = (const float*)d_in[1];
    float* out = (float*)d_out;
    char* ws = (char*)d_ws;
    uint32_t* hist = (uint32_t*)(ws + OFF_HIST);
    float*    med  = (float*)(ws + OFF_MED);
    uint32_t* bbox = (uint32_t*)(ws + OFF_BBOX);
    double*   sums = (double*)(ws + OFF_SUMS);
    uint32_t* gbm  = (uint32_t*)(ws + OFF_BM);

    hipMemsetAsync(ws, 0, WS_USED, stream);
    hipMemsetAsync(ws + OFF_BBOX, 0xFF, 12, stream); // min slots -> +inf encoding

    k_hist  <<<S_FRAMES * 4, 256, 0, stream>>>(conf, hist);
    k_median<<<S_FRAMES,     256, 0, stream>>>(conf, hist, med);
    k_stats <<<2048,         256, 0, stream>>>(pts, conf, med, bbox, sums);
    k_voxel <<<S_FRAMES * 4, 256, 0, stream>>>(pts, conf, med, bbox, gbm);
    k_final <<<S_FRAMES,     256, 0, stream>>>(gbm, sums, out);
}

// Round 2
// 197.914 us; speedup vs baseline: 4.9761x; 4.9761x over previous
//
#include <hip/hip_runtime.h>
#include <cstdint>

#define S_FRAMES 64
#define NPF      147456           // 384*384
#define TOT      (S_FRAMES * NPF) // 9437184
#define NBINS    16384
#define R0       73727u
#define R1       73728u
#define NBLK_STATS 2048

// workspace layout (bytes)
#define OFF_HIST 0
#define SZ_HIST  (S_FRAMES * NBINS * 4)   // 4194304
#define OFF_MED  SZ_HIST                  // 64 floats
#define OFF_BBOX (OFF_MED + 256)          // 6 floats (plain, written by k_reduce)
#define OFF_SUMS (OFF_BBOX + 64)          // 3 doubles: s1, s2, n
#define OFF_PBF  (OFF_SUMS + 64)          // 2048*6 floats
#define OFF_PBD  (OFF_PBF + NBLK_STATS * 6 * 4)   // 2048*2 doubles
#define OFF_PBC  (OFF_PBD + NBLK_STATS * 2 * 8)   // 2048 u32
#define OFF_BM   (OFF_PBC + NBLK_STATS * 4)
#define WORDS_BM 9344                     // 8192 (dim64) + 1024 (dim32) + 128 (dim16)
#define SZ_BM    (S_FRAMES * WORDS_BM * 4)

__device__ __forceinline__ int conf_bin(float v) {
    int b = (int)(v * (float)NBINS);
    return b < 0 ? 0 : (b > NBINS - 1 ? NBINS - 1 : b);
}

// K1a: per-frame conf histogram, 4 blocks/frame, float4 loads
__global__ __launch_bounds__(256) void k_hist(const float* __restrict__ conf,
                                              uint32_t* __restrict__ hist) {
    int f = blockIdx.x >> 2;
    int chunk = blockIdx.x & 3;
    __shared__ uint32_t h[NBINS]; // 64 KB
    for (int i = threadIdx.x; i < NBINS; i += 256) h[i] = 0;
    __syncthreads();
    const float4* c4 = (const float4*)(conf + (size_t)f * NPF + (size_t)chunk * (NPF / 4));
    for (int i = threadIdx.x; i < NPF / 16; i += 256) {
        float4 v = c4[i];
        atomicAdd(&h[conf_bin(v.x)], 1u);
        atomicAdd(&h[conf_bin(v.y)], 1u);
        atomicAdd(&h[conf_bin(v.z)], 1u);
        atomicAdd(&h[conf_bin(v.w)], 1u);
    }
    __syncthreads();
    uint32_t* gh = hist + (size_t)f * NBINS;
    for (int i = threadIdx.x; i < NBINS; i += 256)
        if (h[i]) atomicAdd(&gh[i], h[i]);
}

// K1b: exact median (ranks R0,R1) per frame from histogram + candidate re-scan
__global__ __launch_bounds__(256) void k_median(const float* __restrict__ conf,
                                                const uint32_t* __restrict__ hist,
                                                float* __restrict__ med) {
    int f = blockIdx.x;
    const uint32_t* gh = hist + (size_t)f * NBINS;
    __shared__ uint32_t part[256];
    __shared__ uint32_t excl[256];
    __shared__ int bin0, bin1;
    __shared__ uint32_t cb0, cb1;
    const int base = threadIdx.x * (NBINS / 256);
    uint32_t s = 0;
    for (int j = 0; j < NBINS / 256; j++) s += gh[base + j];
    part[threadIdx.x] = s;
    __syncthreads();
    if (threadIdx.x == 0) {
        uint32_t run = 0;
        for (int t = 0; t < 256; t++) { excl[t] = run; run += part[t]; }
    }
    __syncthreads();
    uint32_t e = excl[threadIdx.x], p = part[threadIdx.x];
    if (R0 >= e && R0 < e + p) {
        uint32_t cum = e;
        for (int j = 0; j < NBINS / 256; j++) {
            uint32_t c2 = gh[base + j];
            if (R0 < cum + c2) { bin0 = base + j; cb0 = cum; break; }
            cum += c2;
        }
    }
    if (R1 >= e && R1 < e + p) {
        uint32_t cum = e;
        for (int j = 0; j < NBINS / 256; j++) {
            uint32_t c2 = gh[base + j];
            if (R1 < cum + c2) { bin1 = base + j; cb1 = cum; break; }
            cum += c2;
        }
    }
    __syncthreads();
    const int CAP = 1024;
    __shared__ float buf0[CAP], buf1[CAP];
    __shared__ uint32_t n0, n1;
    if (threadIdx.x == 0) { n0 = 0; n1 = 0; }
    __syncthreads();
    int b0 = bin0, b1 = bin1;
    const float4* c4 = (const float4*)(conf + (size_t)f * NPF);
    for (int i = threadIdx.x; i < NPF / 4; i += 256) {
        float4 q = c4[i];
        float vv[4] = {q.x, q.y, q.z, q.w};
        #pragma unroll
        for (int j = 0; j < 4; j++) {
            float v = vv[j];
            int b = conf_bin(v);
            if (b == b0) {
                uint32_t k = atomicAdd(&n0, 1u); if (k < CAP) buf0[k] = v;
            } else if (b == b1) {
                uint32_t k = atomicAdd(&n1, 1u); if (k < CAP) buf1[k] = v;
            }
        }
    }
    __syncthreads();
    if (threadIdx.x == 0) {
        int m0 = (int)(n0 < CAP ? n0 : CAP);
        for (int i = 1; i < m0; i++) {
            float key = buf0[i]; int j = i - 1;
            while (j >= 0 && buf0[j] > key) { buf0[j + 1] = buf0[j]; j--; }
            buf0[j + 1] = key;
        }
        float v0 = buf0[R0 - cb0];
        float v1;
        if (b1 == b0) {
            v1 = buf0[R1 - cb0];
        } else {
            int m1 = (int)(n1 < CAP ? n1 : CAP);
            for (int i = 1; i < m1; i++) {
                float key = buf1[i]; int j = i - 1;
                while (j >= 0 && buf1[j] > key) { buf1[j + 1] = buf1[j]; j--; }
                buf1[j + 1] = key;
            }
            v1 = buf1[R1 - cb1];
        }
        med[f] = 0.5f * v0 + 0.5f * v1;
    }
}

// K2: fused bbox (valid pts) + complexity sums (mask pts), block partials (no global atomics)
__global__ __launch_bounds__(256) void k_stats(const float* __restrict__ pts,
                                               const float* __restrict__ conf,
                                               const float* __restrict__ med,
                                               float* __restrict__ pbf,
                                               double* __restrict__ pbd,
                                               uint32_t* __restrict__ pbc) {
    const float4* c4 = (const float4*)conf;
    const float4* p4 = (const float4*)pts;
    int tid = blockIdx.x * blockDim.x + threadIdx.x;
    int stride = gridDim.x * blockDim.x;
    const int NG = TOT / 4; // 2359296 groups of 4 points
    float mnx = 1e30f, mny = 1e30f, mnz = 1e30f;
    float mxx = -1e30f, mxy = -1e30f, mxz = -1e30f;
    double s1 = 0.0, s2 = 0.0;
    uint32_t cnt = 0;
    for (int g = tid; g < NG; g += stride) {
        float4 cc = c4[g];
        float4 a = p4[3 * (size_t)g], b = p4[3 * (size_t)g + 1], d = p4[3 * (size_t)g + 2];
        float cv[4] = {cc.x, cc.y, cc.z, cc.w};
        float v[12] = {a.x, a.y, a.z, a.w, b.x, b.y, b.z, b.w, d.x, d.y, d.z, d.w};
        float q = med[g / (NPF / 4)];
        #pragma unroll
        for (int j = 0; j < 4; j++) {
            float c = cv[j];
            float x = v[3 * j], y = v[3 * j + 1], z = v[3 * j + 2];
            if (c > 0.1f) {
                float dd = sqrtf(x * x + y * y + z * z);
                s1 += (double)dd;
                s2 += (double)dd * (double)dd;
                cnt++;
                if (c >= q) {
                    mnx = fminf(mnx, x); mny = fminf(mny, y); mnz = fminf(mnz, z);
                    mxx = fmaxf(mxx, x); mxy = fmaxf(mxy, y); mxz = fmaxf(mxz, z);
                }
            }
        }
    }
    for (int o = 32; o > 0; o >>= 1) {
        mnx = fminf(mnx, __shfl_xor(mnx, o)); mny = fminf(mny, __shfl_xor(mny, o));
        mnz = fminf(mnz, __shfl_xor(mnz, o));
        mxx = fmaxf(mxx, __shfl_xor(mxx, o)); mxy = fmaxf(mxy, __shfl_xor(mxy, o));
        mxz = fmaxf(mxz, __shfl_xor(mxz, o));
        s1 += __shfl_xor(s1, o); s2 += __shfl_xor(s2, o);
        cnt += __shfl_xor(cnt, o);
    }
    __shared__ float  rf[6][4];
    __shared__ double rd[2][4];
    __shared__ uint32_t rc[4];
    int wave = threadIdx.x >> 6, lane = threadIdx.x & 63;
    if (lane == 0) {
        rf[0][wave] = mnx; rf[1][wave] = mny; rf[2][wave] = mnz;
        rf[3][wave] = mxx; rf[4][wave] = mxy; rf[5][wave] = mxz;
        rd[0][wave] = s1;  rd[1][wave] = s2;  rc[wave] = cnt;
    }
    __syncthreads();
    if (threadIdx.x == 0) {
        float o0 = fminf(fminf(rf[0][0], rf[0][1]), fminf(rf[0][2], rf[0][3]));
        float o1 = fminf(fminf(rf[1][0], rf[1][1]), fminf(rf[1][2], rf[1][3]));
        float o2 = fminf(fminf(rf[2][0], rf[2][1]), fminf(rf[2][2], rf[2][3]));
        float o3 = fmaxf(fmaxf(rf[3][0], rf[3][1]), fmaxf(rf[3][2], rf[3][3]));
        float o4 = fmaxf(fmaxf(rf[4][0], rf[4][1]), fmaxf(rf[4][2], rf[4][3]));
        float o5 = fmaxf(fmaxf(rf[5][0], rf[5][1]), fmaxf(rf[5][2], rf[5][3]));
        size_t b6 = (size_t)blockIdx.x * 6;
        pbf[b6 + 0] = o0; pbf[b6 + 1] = o1; pbf[b6 + 2] = o2;
        pbf[b6 + 3] = o3; pbf[b6 + 4] = o4; pbf[b6 + 5] = o5;
        pbd[(size_t)blockIdx.x * 2]     = rd[0][0] + rd[0][1] + rd[0][2] + rd[0][3];
        pbd[(size_t)blockIdx.x * 2 + 1] = rd[1][0] + rd[1][1] + rd[1][2] + rd[1][3];
        pbc[blockIdx.x] = rc[0] + rc[1] + rc[2] + rc[3];
    }
}

// K2b: fold 2048 block partials -> bbox + sums
__global__ __launch_bounds__(256) void k_reduce(const float* __restrict__ pbf,
                                                const double* __restrict__ pbd,
                                                const uint32_t* __restrict__ pbc,
                                                float* __restrict__ bbox,
                                                double* __restrict__ sums) {
    float mnx = 1e30f, mny = 1e30f, mnz = 1e30f;
    float mxx = -1e30f, mxy = -1e30f, mxz = -1e30f;
    double s1 = 0.0, s2 = 0.0;
    uint32_t cnt = 0;
    for (int b = threadIdx.x; b < NBLK_STATS; b += 256) {
        size_t b6 = (size_t)b * 6;
        mnx = fminf(mnx, pbf[b6 + 0]); mny = fminf(mny, pbf[b6 + 1]);
        mnz = fminf(mnz, pbf[b6 + 2]);
        mxx = fmaxf(mxx, pbf[b6 + 3]); mxy = fmaxf(mxy, pbf[b6 + 4]);
        mxz = fmaxf(mxz, pbf[b6 + 5]);
        s1 += pbd[(size_t)b * 2]; s2 += pbd[(size_t)b * 2 + 1];
        cnt += pbc[b];
    }
    for (int o = 32; o > 0; o >>= 1) {
        mnx = fminf(mnx, __shfl_xor(mnx, o)); mny = fminf(mny, __shfl_xor(mny, o));
        mnz = fminf(mnz, __shfl_xor(mnz, o));
        mxx = fmaxf(mxx, __shfl_xor(mxx, o)); mxy = fmaxf(mxy, __shfl_xor(mxy, o));
        mxz = fmaxf(mxz, __shfl_xor(mxz, o));
        s1 += __shfl_xor(s1, o); s2 += __shfl_xor(s2, o);
        cnt += __shfl_xor(cnt, o);
    }
    __shared__ float  rf[6][4];
    __shared__ double rd[2][4];
    __shared__ uint32_t rc[4];
    int wave = threadIdx.x >> 6, lane = threadIdx.x & 63;
    if (lane == 0) {
        rf[0][wave] = mnx; rf[1][wave] = mny; rf[2][wave] = mnz;
        rf[3][wave] = mxx; rf[4][wave] = mxy; rf[5][wave] = mxz;
        rd[0][wave] = s1;  rd[1][wave] = s2;  rc[wave] = cnt;
    }
    __syncthreads();
    if (threadIdx.x == 0) {
        bbox[0] = fminf(fminf(rf[0][0], rf[0][1]), fminf(rf[0][2], rf[0][3]));
        bbox[1] = fminf(fminf(rf[1][0], rf[1][1]), fminf(rf[1][2], rf[1][3]));
        bbox[2] = fminf(fminf(rf[2][0], rf[2][1]), fminf(rf[2][2], rf[2][3]));
        bbox[3] = fmaxf(fmaxf(rf[3][0], rf[3][1]), fmaxf(rf[3][2], rf[3][3]));
        bbox[4] = fmaxf(fmaxf(rf[4][0], rf[4][1]), fmaxf(rf[4][2], rf[4][3]));
        bbox[5] = fmaxf(fmaxf(rf[5][0], rf[5][1]), fmaxf(rf[5][2], rf[5][3]));
        sums[0] = rd[0][0] + rd[0][1] + rd[0][2] + rd[0][3];
        sums[1] = rd[1][0] + rd[1][1] + rd[1][2] + rd[1][3];
        sums[2] = (double)(rc[0] + rc[1] + rc[2] + rc[3]);
    }
}

// K3: fused 3-scale LDS voxel bitmaps, 8 blocks/frame, OR-merge to global
__global__ __launch_bounds__(256) void k_voxel(const float* __restrict__ pts,
                                               const float* __restrict__ conf,
                                               const float* __restrict__ med,
                                               const float* __restrict__ bbox,
                                               uint32_t* __restrict__ gbm) {
    int f = blockIdx.x >> 3;
    int chunk = blockIdx.x & 7;
    __shared__ uint32_t bm[WORDS_BM]; // [0,8192)=λ40 dim64, [8192,9216)=λ20 dim32, [9216,9344)=λ10 dim16
    for (int i = threadIdx.x; i < WORDS_BM; i += 256) bm[i] = 0;
    float pmnx = bbox[0], pmny = bbox[1], pmnz = bbox[2];
    float ex = bbox[3] - pmnx, ey = bbox[4] - pmny, ez = bbox[5] - pmnz;
    float me = fminf(ex, fminf(ey, ez));
    float i40 = 40.0f / me, i20 = 20.0f / me, i10 = 10.0f / me;
    float q = med[f];
    __syncthreads();
    const size_t base = (size_t)f * NPF + (size_t)chunk * (NPF / 8);
    const float4* c4 = (const float4*)(conf + base);
    const float4* p4 = (const float4*)(pts + base * 3);
    for (int i = threadIdx.x; i < NPF / 32; i += 256) { // groups of 4 points
        float4 cc = c4[i];
        float4 a = p4[3 * (size_t)i], b = p4[3 * (size_t)i + 1], d = p4[3 * (size_t)i + 2];
        float cv[4] = {cc.x, cc.y, cc.z, cc.w};
        float v[12] = {a.x, a.y, a.z, a.w, b.x, b.y, b.z, b.w, d.x, d.y, d.z, d.w};
        #pragma unroll
        for (int j = 0; j < 4; j++) {
            float c = cv[j];
            if (c > 0.1f && c >= q) {
                float x = v[3 * j] - pmnx, y = v[3 * j + 1] - pmny, z = v[3 * j + 2] - pmnz;
                int cx, cy, cz, bit;
                cx = (int)floorf(x * i40); cy = (int)floorf(y * i40); cz = (int)floorf(z * i40);
                cx = min(max(cx, 0), 63); cy = min(max(cy, 0), 63); cz = min(max(cz, 0), 63);
                bit = (cx << 12) | (cy << 6) | cz;
                atomicOr(&bm[bit >> 5], 1u << (bit & 31));
                cx = (int)floorf(x * i20); cy = (int)floorf(y * i20); cz = (int)floorf(z * i20);
                cx = min(max(cx, 0), 31); cy = min(max(cy, 0), 31); cz = min(max(cz, 0), 31);
                bit = (cx << 10) | (cy << 5) | cz;
                atomicOr(&bm[8192 + (bit >> 5)], 1u << (bit & 31));
                cx = (int)floorf(x * i10); cy = (int)floorf(y * i10); cz = (int)floorf(z * i10);
                cx = min(max(cx, 0), 15); cy = min(max(cy, 0), 15); cz = min(max(cz, 0), 15);
                bit = (cx << 8) | (cy << 4) | cz;
                atomicOr(&bm[9216 + (bit >> 5)], 1u << (bit & 31));
            }
        }
    }
    __syncthreads();
    uint32_t* g = gbm + (size_t)f * WORDS_BM;
    for (int i = threadIdx.x; i < WORDS_BM; i += 256) {
        uint32_t v = bm[i];
        if (v) atomicOr(&g[i], v);
    }
}

// K4: popcount per frame -> counts; block 0 finalizes complexity
__global__ __launch_bounds__(256) void k_final(const uint32_t* __restrict__ gbm,
                                               const double* __restrict__ sums,
                                               float* __restrict__ out) {
    int f = blockIdx.x;
    const uint32_t* g = gbm + (size_t)f * WORDS_BM;
    uint32_t c40 = 0, c20 = 0, c10 = 0;
    for (int i = threadIdx.x; i < 8192; i += 256) c40 += __popc(g[i]);
    for (int i = threadIdx.x; i < 1024; i += 256) c20 += __popc(g[8192 + i]);
    for (int i = threadIdx.x; i < 128; i += 256) c10 += __popc(g[9216 + i]);
    for (int o = 32; o > 0; o >>= 1) {
        c40 += __shfl_xor(c40, o);
        c20 += __shfl_xor(c20, o);
        c10 += __shfl_xor(c10, o);
    }
    __shared__ uint32_t red[3][4];
    int wave = threadIdx.x >> 6, lane = threadIdx.x & 63;
    if (lane == 0) { red[0][wave] = c40; red[1][wave] = c20; red[2][wave] = c10; }
    __syncthreads();
    if (threadIdx.x == 0) {
        uint32_t t40 = red[0][0] + red[0][1] + red[0][2] + red[0][3];
        uint32_t t20 = red[1][0] + red[1][1] + red[1][2] + red[1][3];
        uint32_t t10 = red[2][0] + red[2][1] + red[2][2] + red[2][3];
        out[0 * S_FRAMES + f] = (float)t10;
        out[1 * S_FRAMES + f] = (float)t20;
        out[2 * S_FRAMES + f] = (float)t40;
        out[3 * S_FRAMES + f] = (float)t20; // adaptive lambda == 20
        if (f == 0) {
            double n = sums[2];
            double s1 = sums[0], s2 = sums[1];
            double mean = s1 / n;
            double var = (s2 - n * mean * mean) / (n - 1.0);
            out[4 * S_FRAMES] = (float)(sqrt(var) * (n / (double)TOT));
        }
    }
}

extern "C" void kernel_launch(void* const* d_in, const int* in_sizes, int n_in,
                              void* d_out, int out_size, void* d_ws, size_t ws_size,
                              hipStream_t stream) {
    const float* pts  = (const float*)d_in[0];
    const float* conf = (const float*)d_in[1];
    float* out = (float*)d_out;
    char* ws = (char*)d_ws;
    uint32_t* hist = (uint32_t*)(ws + OFF_HIST);
    float*    med  = (float*)(ws + OFF_MED);
    float*    bbox = (float*)(ws + OFF_BBOX);
    double*   sums = (double*)(ws + OFF_SUMS);
    float*    pbf  = (float*)(ws + OFF_PBF);
    double*   pbd  = (double*)(ws + OFF_PBD);
    uint32_t* pbc  = (uint32_t*)(ws + OFF_PBC);
    uint32_t* gbm  = (uint32_t*)(ws + OFF_BM);

    hipMemsetAsync(ws + OFF_HIST, 0, SZ_HIST, stream);
    hipMemsetAsync(ws + OFF_BM, 0, SZ_BM, stream);

    k_hist  <<<S_FRAMES * 4, 256, 0, stream>>>(conf, hist);
    k_median<<<S_FRAMES,     256, 0, stream>>>(conf, hist, med);
    k_stats <<<NBLK_STATS,   256, 0, stream>>>(pts, conf, med, pbf, pbd, pbc);
    k_reduce<<<1,            256, 0, stream>>>(pbf, pbd, pbc, bbox, sums);
    k_voxel <<<S_FRAMES * 8, 256, 0, stream>>>(pts, conf, med, bbox, gbm);
    k_final <<<S_FRAMES,     256, 0, stream>>>(gbm, sums, out);
}

// Round 3
// 158.063 us; speedup vs baseline: 6.2306x; 1.2521x over previous
//
#include <hip/hip_runtime.h>
#include <cstdint>

#define S_FRAMES 64
#define NPF      147456           // 384*384
#define TOT      (S_FRAMES * NPF) // 9437184
#define NBINS    16384
#define R0       73727u
#define R1       73728u
#define NBLK_STATS 2048
#define CAP      1024

// workspace layout (bytes)
#define OFF_HIST 0
#define SZ_HIST  (S_FRAMES * NBINS * 4)   // 4194304
#define OFF_MED  SZ_HIST                  // 64 floats
#define OFF_BBOX (OFF_MED + 256)          // 6 floats
#define OFF_SUMS (OFF_BBOX + 64)          // 3 doubles: s1, s2, n
#define OFF_PBF  (OFF_SUMS + 64)          // 2048*6 floats
#define OFF_PBD  (OFF_PBF + NBLK_STATS * 6 * 4)
#define OFF_PBC  (OFF_PBD + NBLK_STATS * 2 * 8)
#define OFF_HDR  (OFF_PBC + NBLK_STATS * 4)       // 64 * 4 u32 {bin0,bin1,cb0,cb1}
#define OFF_CCNT (OFF_HDR + S_FRAMES * 16)        // 64 * 2 u32 (zeroed)
#define OFF_CAND (OFF_CCNT + S_FRAMES * 8)        // 64 * 2 * CAP floats
#define OFF_BM   (OFF_CAND + S_FRAMES * 2 * CAP * 4)
#define WORDS_BM 9344                     // 8192 (dim64) + 1024 (dim32) + 128 (dim16)
#define SZ_BM    (S_FRAMES * WORDS_BM * 4)

__device__ __forceinline__ int conf_bin(float v) {
    int b = (int)(v * (float)NBINS);
    return b < 0 ? 0 : (b > NBINS - 1 ? NBINS - 1 : b);
}

// K1a: per-frame conf histogram, 4 blocks/frame, float4 loads
__global__ __launch_bounds__(256) void k_hist(const float* __restrict__ conf,
                                              uint32_t* __restrict__ hist) {
    int f = blockIdx.x >> 2;
    int chunk = blockIdx.x & 3;
    __shared__ uint32_t h[NBINS]; // 64 KB
    for (int i = threadIdx.x; i < NBINS; i += 256) h[i] = 0;
    __syncthreads();
    const float4* c4 = (const float4*)(conf + (size_t)f * NPF + (size_t)chunk * (NPF / 4));
    for (int i = threadIdx.x; i < NPF / 16; i += 256) {
        float4 v = c4[i];
        atomicAdd(&h[conf_bin(v.x)], 1u);
        atomicAdd(&h[conf_bin(v.y)], 1u);
        atomicAdd(&h[conf_bin(v.z)], 1u);
        atomicAdd(&h[conf_bin(v.w)], 1u);
    }
    __syncthreads();
    uint32_t* gh = hist + (size_t)f * NBINS;
    for (int i = threadIdx.x; i < NBINS; i += 256)
        if (h[i]) atomicAdd(&gh[i], h[i]);
}

// K1b: locate rank bins from histogram -> per-frame header
__global__ __launch_bounds__(256) void k_findbin(const uint32_t* __restrict__ hist,
                                                 uint32_t* __restrict__ hdr) {
    int f = blockIdx.x;
    const uint32_t* gh = hist + (size_t)f * NBINS;
    __shared__ uint32_t part[256];
    __shared__ uint32_t excl[256];
    __shared__ uint32_t hb[4]; // bin0, bin1, cb0, cb1
    const int base = threadIdx.x * (NBINS / 256);
    uint32_t s = 0;
    for (int j = 0; j < NBINS / 256; j++) s += gh[base + j];
    part[threadIdx.x] = s;
    __syncthreads();
    if (threadIdx.x == 0) {
        uint32_t run = 0;
        for (int t = 0; t < 256; t++) { excl[t] = run; run += part[t]; }
    }
    __syncthreads();
    uint32_t e = excl[threadIdx.x], p = part[threadIdx.x];
    if (R0 >= e && R0 < e + p) {
        uint32_t cum = e;
        for (int j = 0; j < NBINS / 256; j++) {
            uint32_t c2 = gh[base + j];
            if (R0 < cum + c2) { hb[0] = base + j; hb[2] = cum; break; }
            cum += c2;
        }
    }
    if (R1 >= e && R1 < e + p) {
        uint32_t cum = e;
        for (int j = 0; j < NBINS / 256; j++) {
            uint32_t c2 = gh[base + j];
            if (R1 < cum + c2) { hb[1] = base + j; hb[3] = cum; break; }
            cum += c2;
        }
    }
    __syncthreads();
    if (threadIdx.x < 4) hdr[f * 4 + threadIdx.x] = hb[threadIdx.x];
}

// K1c: collect candidate values in rank bins, 8 blocks/frame, full-chip parallel
__global__ __launch_bounds__(256) void k_collect(const float* __restrict__ conf,
                                                 const uint32_t* __restrict__ hdr,
                                                 uint32_t* __restrict__ ccnt,
                                                 float* __restrict__ cand) {
    int f = blockIdx.x >> 3;
    int chunk = blockIdx.x & 7;
    int b0 = (int)hdr[f * 4 + 0], b1 = (int)hdr[f * 4 + 1];
    float* buf0 = cand + (size_t)f * 2 * CAP;
    float* buf1 = buf0 + CAP;
    uint32_t* n0 = &ccnt[f * 2];
    uint32_t* n1 = &ccnt[f * 2 + 1];
    const float4* c4 = (const float4*)(conf + (size_t)f * NPF + (size_t)chunk * (NPF / 8));
    for (int i = threadIdx.x; i < NPF / 32; i += 256) {
        float4 q = c4[i];
        float vv[4] = {q.x, q.y, q.z, q.w};
        #pragma unroll
        for (int j = 0; j < 4; j++) {
            float v = vv[j];
            int b = conf_bin(v);
            if (b == b0) {
                uint32_t k = atomicAdd(n0, 1u); if (k < CAP) buf0[k] = v;
            } else if (b == b1) {
                uint32_t k = atomicAdd(n1, 1u); if (k < CAP) buf1[k] = v;
            }
        }
    }
}

// K1d: sort candidates, pick ranks -> median
__global__ __launch_bounds__(64) void k_select(const uint32_t* __restrict__ hdr,
                                               const uint32_t* __restrict__ ccnt,
                                               const float* __restrict__ cand,
                                               float* __restrict__ med) {
    int f = blockIdx.x;
    if (threadIdx.x != 0) return;
    int b0 = (int)hdr[f * 4 + 0], b1 = (int)hdr[f * 4 + 1];
    uint32_t cb0 = hdr[f * 4 + 2], cb1 = hdr[f * 4 + 3];
    const float* gbuf0 = cand + (size_t)f * 2 * CAP;
    const float* gbuf1 = gbuf0 + CAP;
    float buf[256];
    int m0 = (int)min(ccnt[f * 2], (uint32_t)256);
    for (int i = 0; i < m0; i++) buf[i] = gbuf0[i];
    for (int i = 1; i < m0; i++) {
        float key = buf[i]; int j = i - 1;
        while (j >= 0 && buf[j] > key) { buf[j + 1] = buf[j]; j--; }
        buf[j + 1] = key;
    }
    float v0 = buf[R0 - cb0];
    float v1;
    if (b1 == b0) {
        v1 = buf[R1 - cb0];
    } else {
        int m1 = (int)min(ccnt[f * 2 + 1], (uint32_t)256);
        float bufb[256];
        for (int i = 0; i < m1; i++) bufb[i] = gbuf1[i];
        for (int i = 1; i < m1; i++) {
            float key = bufb[i]; int j = i - 1;
            while (j >= 0 && bufb[j] > key) { bufb[j + 1] = bufb[j]; j--; }
            bufb[j + 1] = key;
        }
        v1 = bufb[R1 - cb1];
    }
    med[f] = 0.5f * v0 + 0.5f * v1;
}

// K2: fused bbox (valid pts) + complexity sums (mask pts), block partials
__global__ __launch_bounds__(256) void k_stats(const float* __restrict__ pts,
                                               const float* __restrict__ conf,
                                               const float* __restrict__ med,
                                               float* __restrict__ pbf,
                                               double* __restrict__ pbd,
                                               uint32_t* __restrict__ pbc) {
    const float4* c4 = (const float4*)conf;
    const float4* p4 = (const float4*)pts;
    int tid = blockIdx.x * blockDim.x + threadIdx.x;
    int stride = gridDim.x * blockDim.x;
    const int NG = TOT / 4;
    float mnx = 1e30f, mny = 1e30f, mnz = 1e30f;
    float mxx = -1e30f, mxy = -1e30f, mxz = -1e30f;
    double s1 = 0.0, s2 = 0.0;
    uint32_t cnt = 0;
    for (int g = tid; g < NG; g += stride) {
        float4 cc = c4[g];
        float4 a = p4[3 * (size_t)g], b = p4[3 * (size_t)g + 1], d = p4[3 * (size_t)g + 2];
        float cv[4] = {cc.x, cc.y, cc.z, cc.w};
        float v[12] = {a.x, a.y, a.z, a.w, b.x, b.y, b.z, b.w, d.x, d.y, d.z, d.w};
        float q = med[g / (NPF / 4)];
        #pragma unroll
        for (int j = 0; j < 4; j++) {
            float c = cv[j];
            float x = v[3 * j], y = v[3 * j + 1], z = v[3 * j + 2];
            if (c > 0.1f) {
                float dd = sqrtf(x * x + y * y + z * z);
                s1 += (double)dd;
                s2 += (double)dd * (double)dd;
                cnt++;
                if (c >= q) {
                    mnx = fminf(mnx, x); mny = fminf(mny, y); mnz = fminf(mnz, z);
                    mxx = fmaxf(mxx, x); mxy = fmaxf(mxy, y); mxz = fmaxf(mxz, z);
                }
            }
        }
    }
    for (int o = 32; o > 0; o >>= 1) {
        mnx = fminf(mnx, __shfl_xor(mnx, o)); mny = fminf(mny, __shfl_xor(mny, o));
        mnz = fminf(mnz, __shfl_xor(mnz, o));
        mxx = fmaxf(mxx, __shfl_xor(mxx, o)); mxy = fmaxf(mxy, __shfl_xor(mxy, o));
        mxz = fmaxf(mxz, __shfl_xor(mxz, o));
        s1 += __shfl_xor(s1, o); s2 += __shfl_xor(s2, o);
        cnt += __shfl_xor(cnt, o);
    }
    __shared__ float  rf[6][4];
    __shared__ double rd[2][4];
    __shared__ uint32_t rc[4];
    int wave = threadIdx.x >> 6, lane = threadIdx.x & 63;
    if (lane == 0) {
        rf[0][wave] = mnx; rf[1][wave] = mny; rf[2][wave] = mnz;
        rf[3][wave] = mxx; rf[4][wave] = mxy; rf[5][wave] = mxz;
        rd[0][wave] = s1;  rd[1][wave] = s2;  rc[wave] = cnt;
    }
    __syncthreads();
    if (threadIdx.x == 0) {
        size_t b6 = (size_t)blockIdx.x * 6;
        pbf[b6 + 0] = fminf(fminf(rf[0][0], rf[0][1]), fminf(rf[0][2], rf[0][3]));
        pbf[b6 + 1] = fminf(fminf(rf[1][0], rf[1][1]), fminf(rf[1][2], rf[1][3]));
        pbf[b6 + 2] = fminf(fminf(rf[2][0], rf[2][1]), fminf(rf[2][2], rf[2][3]));
        pbf[b6 + 3] = fmaxf(fmaxf(rf[3][0], rf[3][1]), fmaxf(rf[3][2], rf[3][3]));
        pbf[b6 + 4] = fmaxf(fmaxf(rf[4][0], rf[4][1]), fmaxf(rf[4][2], rf[4][3]));
        pbf[b6 + 5] = fmaxf(fmaxf(rf[5][0], rf[5][1]), fmaxf(rf[5][2], rf[5][3]));
        pbd[(size_t)blockIdx.x * 2]     = rd[0][0] + rd[0][1] + rd[0][2] + rd[0][3];
        pbd[(size_t)blockIdx.x * 2 + 1] = rd[1][0] + rd[1][1] + rd[1][2] + rd[1][3];
        pbc[blockIdx.x] = rc[0] + rc[1] + rc[2] + rc[3];
    }
}

// K2b: fold 2048 block partials -> bbox + sums
__global__ __launch_bounds__(256) void k_reduce(const float* __restrict__ pbf,
                                                const double* __restrict__ pbd,
                                                const uint32_t* __restrict__ pbc,
                                                float* __restrict__ bbox,
                                                double* __restrict__ sums) {
    float mnx = 1e30f, mny = 1e30f, mnz = 1e30f;
    float mxx = -1e30f, mxy = -1e30f, mxz = -1e30f;
    double s1 = 0.0, s2 = 0.0;
    uint32_t cnt = 0;
    for (int b = threadIdx.x; b < NBLK_STATS; b += 256) {
        size_t b6 = (size_t)b * 6;
        mnx = fminf(mnx, pbf[b6 + 0]); mny = fminf(mny, pbf[b6 + 1]);
        mnz = fminf(mnz, pbf[b6 + 2]);
        mxx = fmaxf(mxx, pbf[b6 + 3]); mxy = fmaxf(mxy, pbf[b6 + 4]);
        mxz = fmaxf(mxz, pbf[b6 + 5]);
        s1 += pbd[(size_t)b * 2]; s2 += pbd[(size_t)b * 2 + 1];
        cnt += pbc[b];
    }
    for (int o = 32; o > 0; o >>= 1) {
        mnx = fminf(mnx, __shfl_xor(mnx, o)); mny = fminf(mny, __shfl_xor(mny, o));
        mnz = fminf(mnz, __shfl_xor(mnz, o));
        mxx = fmaxf(mxx, __shfl_xor(mxx, o)); mxy = fmaxf(mxy, __shfl_xor(mxy, o));
        mxz = fmaxf(mxz, __shfl_xor(mxz, o));
        s1 += __shfl_xor(s1, o); s2 += __shfl_xor(s2, o);
        cnt += __shfl_xor(cnt, o);
    }
    __shared__ float  rf[6][4];
    __shared__ double rd[2][4];
    __shared__ uint32_t rc[4];
    int wave = threadIdx.x >> 6, lane = threadIdx.x & 63;
    if (lane == 0) {
        rf[0][wave] = mnx; rf[1][wave] = mny; rf[2][wave] = mnz;
        rf[3][wave] = mxx; rf[4][wave] = mxy; rf[5][wave] = mxz;
        rd[0][wave] = s1;  rd[1][wave] = s2;  rc[wave] = cnt;
    }
    __syncthreads();
    if (threadIdx.x == 0) {
        bbox[0] = fminf(fminf(rf[0][0], rf[0][1]), fminf(rf[0][2], rf[0][3]));
        bbox[1] = fminf(fminf(rf[1][0], rf[1][1]), fminf(rf[1][2], rf[1][3]));
        bbox[2] = fminf(fminf(rf[2][0], rf[2][1]), fminf(rf[2][2], rf[2][3]));
        bbox[3] = fmaxf(fmaxf(rf[3][0], rf[3][1]), fmaxf(rf[3][2], rf[3][3]));
        bbox[4] = fmaxf(fmaxf(rf[4][0], rf[4][1]), fmaxf(rf[4][2], rf[4][3]));
        bbox[5] = fmaxf(fmaxf(rf[5][0], rf[5][1]), fmaxf(rf[5][2], rf[5][3]));
        sums[0] = rd[0][0] + rd[0][1] + rd[0][2] + rd[0][3];
        sums[1] = rd[1][0] + rd[1][1] + rd[1][2] + rd[1][3];
        sums[2] = (double)(rc[0] + rc[1] + rc[2] + rc[3]);
    }
}

// K3: fused 3-scale LDS voxel bitmaps, 8 blocks/frame, OR-merge to global
__global__ __launch_bounds__(256) void k_voxel(const float* __restrict__ pts,
                                               const float* __restrict__ conf,
                                               const float* __restrict__ med,
                                               const float* __restrict__ bbox,
                                               uint32_t* __restrict__ gbm) {
    int f = blockIdx.x >> 3;
    int chunk = blockIdx.x & 7;
    __shared__ uint32_t bm[WORDS_BM];
    for (int i = threadIdx.x; i < WORDS_BM; i += 256) bm[i] = 0;
    float pmnx = bbox[0], pmny = bbox[1], pmnz = bbox[2];
    float ex = bbox[3] - pmnx, ey = bbox[4] - pmny, ez = bbox[5] - pmnz;
    float me = fminf(ex, fminf(ey, ez));
    float i40 = 40.0f / me, i20 = 20.0f / me, i10 = 10.0f / me;
    float q = med[f];
    __syncthreads();
    const size_t base = (size_t)f * NPF + (size_t)chunk * (NPF / 8);
    const float4* c4 = (const float4*)(conf + base);
    const float4* p4 = (const float4*)(pts + base * 3);
    for (int i = threadIdx.x; i < NPF / 32; i += 256) {
        float4 cc = c4[i];
        float4 a = p4[3 * (size_t)i], b = p4[3 * (size_t)i + 1], d = p4[3 * (size_t)i + 2];
        float cv[4] = {cc.x, cc.y, cc.z, cc.w};
        float v[12] = {a.x, a.y, a.z, a.w, b.x, b.y, b.z, b.w, d.x, d.y, d.z, d.w};
        #pragma unroll
        for (int j = 0; j < 4; j++) {
            float c = cv[j];
            if (c > 0.1f && c >= q) {
                float x = v[3 * j] - pmnx, y = v[3 * j + 1] - pmny, z = v[3 * j + 2] - pmnz;
                int cx, cy, cz, bit;
                cx = (int)floorf(x * i40); cy = (int)floorf(y * i40); cz = (int)floorf(z * i40);
                cx = min(max(cx, 0), 63); cy = min(max(cy, 0), 63); cz = min(max(cz, 0), 63);
                bit = (cx << 12) | (cy << 6) | cz;
                atomicOr(&bm[bit >> 5], 1u << (bit & 31));
                cx = (int)floorf(x * i20); cy = (int)floorf(y * i20); cz = (int)floorf(z * i20);
                cx = min(max(cx, 0), 31); cy = min(max(cy, 0), 31); cz = min(max(cz, 0), 31);
                bit = (cx << 10) | (cy << 5) | cz;
                atomicOr(&bm[8192 + (bit >> 5)], 1u << (bit & 31));
                cx = (int)floorf(x * i10); cy = (int)floorf(y * i10); cz = (int)floorf(z * i10);
                cx = min(max(cx, 0), 15); cy = min(max(cy, 0), 15); cz = min(max(cz, 0), 15);
                bit = (cx << 8) | (cy << 4) | cz;
                atomicOr(&bm[9216 + (bit >> 5)], 1u << (bit & 31));
            }
        }
    }
    __syncthreads();
    uint32_t* g = gbm + (size_t)f * WORDS_BM;
    for (int i = threadIdx.x; i < WORDS_BM; i += 256) {
        uint32_t v = bm[i];
        if (v) atomicOr(&g[i], v);
    }
}

// K4: popcount per frame -> counts; block 0 finalizes complexity
__global__ __launch_bounds__(256) void k_final(const uint32_t* __restrict__ gbm,
                                               const double* __restrict__ sums,
                                               float* __restrict__ out) {
    int f = blockIdx.x;
    const uint32_t* g = gbm + (size_t)f * WORDS_BM;
    uint32_t c40 = 0, c20 = 0, c10 = 0;
    for (int i = threadIdx.x; i < 8192; i += 256) c40 += __popc(g[i]);
    for (int i = threadIdx.x; i < 1024; i += 256) c20 += __popc(g[8192 + i]);
    for (int i = threadIdx.x; i < 128; i += 256) c10 += __popc(g[9216 + i]);
    for (int o = 32; o > 0; o >>= 1) {
        c40 += __shfl_xor(c40, o);
        c20 += __shfl_xor(c20, o);
        c10 += __shfl_xor(c10, o);
    }
    __shared__ uint32_t red[3][4];
    int wave = threadIdx.x >> 6, lane = threadIdx.x & 63;
    if (lane == 0) { red[0][wave] = c40; red[1][wave] = c20; red[2][wave] = c10; }
    __syncthreads();
    if (threadIdx.x == 0) {
        uint32_t t40 = red[0][0] + red[0][1] + red[0][2] + red[0][3];
        uint32_t t20 = red[1][0] + red[1][1] + red[1][2] + red[1][3];
        uint32_t t10 = red[2][0] + red[2][1] + red[2][2] + red[2][3];
        out[0 * S_FRAMES + f] = (float)t10;
        out[1 * S_FRAMES + f] = (float)t20;
        out[2 * S_FRAMES + f] = (float)t40;
        out[3 * S_FRAMES + f] = (float)t20; // adaptive lambda == 20
        if (f == 0) {
            double n = sums[2];
            double s1 = sums[0], s2 = sums[1];
            double mean = s1 / n;
            double var = (s2 - n * mean * mean) / (n - 1.0);
            out[4 * S_FRAMES] = (float)(sqrt(var) * (n / (double)TOT));
        }
    }
}

extern "C" void kernel_launch(void* const* d_in, const int* in_sizes, int n_in,
                              void* d_out, int out_size, void* d_ws, size_t ws_size,
                              hipStream_t stream) {
    const float* pts  = (const float*)d_in[0];
    const float* conf = (const float*)d_in[1];
    float* out = (float*)d_out;
    char* ws = (char*)d_ws;
    uint32_t* hist = (uint32_t*)(ws + OFF_HIST);
    float*    med  = (float*)(ws + OFF_MED);
    float*    bbox = (float*)(ws + OFF_BBOX);
    double*   sums = (double*)(ws + OFF_SUMS);
    float*    pbf  = (float*)(ws + OFF_PBF);
    double*   pbd  = (double*)(ws + OFF_PBD);
    uint32_t* pbc  = (uint32_t*)(ws + OFF_PBC);
    uint32_t* hdr  = (uint32_t*)(ws + OFF_HDR);
    uint32_t* ccnt = (uint32_t*)(ws + OFF_CCNT);
    float*    cand = (float*)(ws + OFF_CAND);
    uint32_t* gbm  = (uint32_t*)(ws + OFF_BM);

    hipMemsetAsync(ws + OFF_HIST, 0, SZ_HIST, stream);
    hipMemsetAsync(ws + OFF_CCNT, 0, S_FRAMES * 8, stream);
    hipMemsetAsync(ws + OFF_BM, 0, SZ_BM, stream);

    k_hist   <<<S_FRAMES * 4, 256, 0, stream>>>(conf, hist);
    k_findbin<<<S_FRAMES,     256, 0, stream>>>(hist, hdr);
    k_collect<<<S_FRAMES * 8, 256, 0, stream>>>(conf, hdr, ccnt, cand);
    k_select <<<S_FRAMES,      64, 0, stream>>>(hdr, ccnt, cand, med);
    k_stats  <<<NBLK_STATS,   256, 0, stream>>>(pts, conf, med, pbf, pbd, pbc);
    k_reduce <<<1,            256, 0, stream>>>(pbf, pbd, pbc, bbox, sums);
    k_voxel  <<<S_FRAMES * 8, 256, 0, stream>>>(pts, conf, med, bbox, gbm);
    k_final  <<<S_FRAMES,     256, 0, stream>>>(gbm, sums, out);
}

// Round 4
// 144.629 us; speedup vs baseline: 6.8094x; 1.0929x over previous
//
#include <hip/hip_runtime.h>
#include <cstdint>

#define S_FRAMES 64
#define NPF      147456           // 384*384
#define TOT      (S_FRAMES * NPF) // 9437184
#define NBINS    16384
#define R0       73727u
#define R1       73728u
#define NBLK_STATS 2048
#define NBLK_HIST  256            // 4 per frame
#define CAP      1024

// workspace layout (bytes)
#define OFF_HIST 0
#define SZ_HIST  (NBLK_HIST * NBINS * 4)  // 16 MB: per-block slices, no pre-zero needed
#define OFF_MED  SZ_HIST                  // 64 floats
#define OFF_BBOX (OFF_MED + 256)          // 6 floats
#define OFF_SUMS (OFF_BBOX + 64)          // 3 doubles: s1, s2, n
#define OFF_PBF  (OFF_SUMS + 64)          // 2048*6 floats
#define OFF_PBD  (OFF_PBF + NBLK_STATS * 6 * 4)
#define OFF_PBC  (OFF_PBD + NBLK_STATS * 2 * 8)
#define OFF_HDR  (OFF_PBC + NBLK_STATS * 4)       // 64 * 4 u32 {bin0,bin1,cb0,cb1}
#define OFF_CCNT (OFF_HDR + S_FRAMES * 16)        // 64 * 2 u32 (zeroed by k_findbin)
#define OFF_CAND (OFF_CCNT + S_FRAMES * 8)        // 64 * 2 * CAP floats
#define OFF_BM   (OFF_CAND + S_FRAMES * 2 * CAP * 4)
#define WORDS_BM 9344                     // 8192 (dim64) + 1024 (dim32) + 128 (dim16)
#define TOT_BM_WORDS (S_FRAMES * WORDS_BM)

__device__ __forceinline__ int conf_bin(float v) {
    int b = (int)(v * (float)NBINS);
    return b < 0 ? 0 : (b > NBINS - 1 ? NBINS - 1 : b);
}

// K1a: per-frame conf histogram, 4 blocks/frame, float4 loads.
// Each block stores its own hist slice (plain stores). Also zeroes gbm.
__global__ __launch_bounds__(256) void k_hist(const float* __restrict__ conf,
                                              uint32_t* __restrict__ hist,
                                              uint32_t* __restrict__ gbm) {
    // zero the voxel bitmap region (used by k_voxel later in the stream)
    for (int i = blockIdx.x * 256 + threadIdx.x; i < TOT_BM_WORDS; i += NBLK_HIST * 256)
        gbm[i] = 0u;

    int f = blockIdx.x >> 2;
    int chunk = blockIdx.x & 3;
    __shared__ uint32_t h[NBINS]; // 64 KB
    for (int i = threadIdx.x; i < NBINS; i += 256) h[i] = 0;
    __syncthreads();
    const float4* c4 = (const float4*)(conf + (size_t)f * NPF + (size_t)chunk * (NPF / 4));
    for (int i = threadIdx.x; i < NPF / 16; i += 256) {
        float4 v = c4[i];
        atomicAdd(&h[conf_bin(v.x)], 1u);
        atomicAdd(&h[conf_bin(v.y)], 1u);
        atomicAdd(&h[conf_bin(v.z)], 1u);
        atomicAdd(&h[conf_bin(v.w)], 1u);
    }
    __syncthreads();
    uint32_t* gh = hist + (size_t)blockIdx.x * NBINS;
    for (int i = threadIdx.x; i < NBINS; i += 256) gh[i] = h[i];
}

// K1b: sum 4 slices -> LDS hist, locate rank bins -> header; zero ccnt
__global__ __launch_bounds__(256) void k_findbin(const uint32_t* __restrict__ hist,
                                                 uint32_t* __restrict__ hdr,
                                                 uint32_t* __restrict__ ccnt) {
    int f = blockIdx.x;
    const uint32_t* g0 = hist + (size_t)(4 * f + 0) * NBINS;
    const uint32_t* g1 = hist + (size_t)(4 * f + 1) * NBINS;
    const uint32_t* g2 = hist + (size_t)(4 * f + 2) * NBINS;
    const uint32_t* g3 = hist + (size_t)(4 * f + 3) * NBINS;
    __shared__ uint32_t h[NBINS]; // 64 KB
    for (int i = threadIdx.x; i < NBINS; i += 256)
        h[i] = g0[i] + g1[i] + g2[i] + g3[i];
    __syncthreads();
    __shared__ uint32_t part[256];
    __shared__ uint32_t excl[256];
    __shared__ uint32_t hb[4]; // bin0, bin1, cb0, cb1
    const int base = threadIdx.x * (NBINS / 256);
    uint32_t s = 0;
    for (int j = 0; j < NBINS / 256; j++) s += h[base + j];
    part[threadIdx.x] = s;
    __syncthreads();
    if (threadIdx.x == 0) {
        uint32_t run = 0;
        for (int t = 0; t < 256; t++) { excl[t] = run; run += part[t]; }
    }
    __syncthreads();
    uint32_t e = excl[threadIdx.x], p = part[threadIdx.x];
    if (R0 >= e && R0 < e + p) {
        uint32_t cum = e;
        for (int j = 0; j < NBINS / 256; j++) {
            uint32_t c2 = h[base + j];
            if (R0 < cum + c2) { hb[0] = base + j; hb[2] = cum; break; }
            cum += c2;
        }
    }
    if (R1 >= e && R1 < e + p) {
        uint32_t cum = e;
        for (int j = 0; j < NBINS / 256; j++) {
            uint32_t c2 = h[base + j];
            if (R1 < cum + c2) { hb[1] = base + j; hb[3] = cum; break; }
            cum += c2;
        }
    }
    __syncthreads();
    if (threadIdx.x < 4) hdr[f * 4 + threadIdx.x] = hb[threadIdx.x];
    if (threadIdx.x < 2) ccnt[f * 2 + threadIdx.x] = 0u; // init for k_collect
}

// K1c: collect candidate values in rank bins, 8 blocks/frame
__global__ __launch_bounds__(256) void k_collect(const float* __restrict__ conf,
                                                 const uint32_t* __restrict__ hdr,
                                                 uint32_t* __restrict__ ccnt,
                                                 float* __restrict__ cand) {
    int f = blockIdx.x >> 3;
    int chunk = blockIdx.x & 7;
    int b0 = (int)hdr[f * 4 + 0], b1 = (int)hdr[f * 4 + 1];
    float* buf0 = cand + (size_t)f * 2 * CAP;
    float* buf1 = buf0 + CAP;
    uint32_t* n0 = &ccnt[f * 2];
    uint32_t* n1 = &ccnt[f * 2 + 1];
    const float4* c4 = (const float4*)(conf + (size_t)f * NPF + (size_t)chunk * (NPF / 8));
    for (int i = threadIdx.x; i < NPF / 32; i += 256) {
        float4 q = c4[i];
        float vv[4] = {q.x, q.y, q.z, q.w};
        #pragma unroll
        for (int j = 0; j < 4; j++) {
            float v = vv[j];
            int b = conf_bin(v);
            if (b == b0) {
                uint32_t k = atomicAdd(n0, 1u); if (k < CAP) buf0[k] = v;
            } else if (b == b1) {
                uint32_t k = atomicAdd(n1, 1u); if (k < CAP) buf1[k] = v;
            }
        }
    }
}

// K1d: sort candidates, pick ranks -> median
__global__ __launch_bounds__(64) void k_select(const uint32_t* __restrict__ hdr,
                                               const uint32_t* __restrict__ ccnt,
                                               const float* __restrict__ cand,
                                               float* __restrict__ med) {
    int f = blockIdx.x;
    if (threadIdx.x != 0) return;
    int b0 = (int)hdr[f * 4 + 0], b1 = (int)hdr[f * 4 + 1];
    uint32_t cb0 = hdr[f * 4 + 2], cb1 = hdr[f * 4 + 3];
    const float* gbuf0 = cand + (size_t)f * 2 * CAP;
    const float* gbuf1 = gbuf0 + CAP;
    float buf[256];
    int m0 = (int)min(ccnt[f * 2], (uint32_t)256);
    for (int i = 0; i < m0; i++) buf[i] = gbuf0[i];
    for (int i = 1; i < m0; i++) {
        float key = buf[i]; int j = i - 1;
        while (j >= 0 && buf[j] > key) { buf[j + 1] = buf[j]; j--; }
        buf[j + 1] = key;
    }
    float v0 = buf[R0 - cb0];
    float v1;
    if (b1 == b0) {
        v1 = buf[R1 - cb0];
    } else {
        int m1 = (int)min(ccnt[f * 2 + 1], (uint32_t)256);
        float bufb[256];
        for (int i = 0; i < m1; i++) bufb[i] = gbuf1[i];
        for (int i = 1; i < m1; i++) {
            float key = bufb[i]; int j = i - 1;
            while (j >= 0 && bufb[j] > key) { bufb[j + 1] = bufb[j]; j--; }
            bufb[j + 1] = key;
        }
        v1 = bufb[R1 - cb1];
    }
    med[f] = 0.5f * v0 + 0.5f * v1;
}

// K2: fused bbox (valid pts) + complexity sums (mask pts), block partials.
// 32 blocks per frame -> med loaded once per block.
__global__ __launch_bounds__(256) void k_stats(const float* __restrict__ pts,
                                               const float* __restrict__ conf,
                                               const float* __restrict__ med,
                                               float* __restrict__ pbf,
                                               double* __restrict__ pbd,
                                               uint32_t* __restrict__ pbc) {
    int f = blockIdx.x >> 5;
    int chunk = blockIdx.x & 31;
    const int GPB = NPF / 4 / 32; // 1152 float4-groups per block
    const size_t gbase = (size_t)f * (NPF / 4) + (size_t)chunk * GPB;
    const float4* c4 = (const float4*)conf + gbase;
    const float4* p4 = (const float4*)pts + gbase * 3;
    float q = med[f];
    float mnx = 1e30f, mny = 1e30f, mnz = 1e30f;
    float mxx = -1e30f, mxy = -1e30f, mxz = -1e30f;
    double s1 = 0.0, s2 = 0.0;
    uint32_t cnt = 0;
    for (int g = threadIdx.x; g < GPB; g += 256) {
        float4 cc = c4[g];
        float4 a = p4[3 * (size_t)g], b = p4[3 * (size_t)g + 1], d = p4[3 * (size_t)g + 2];
        float cv[4] = {cc.x, cc.y, cc.z, cc.w};
        float v[12] = {a.x, a.y, a.z, a.w, b.x, b.y, b.z, b.w, d.x, d.y, d.z, d.w};
        #pragma unroll
        for (int j = 0; j < 4; j++) {
            float c = cv[j];
            float x = v[3 * j], y = v[3 * j + 1], z = v[3 * j + 2];
            if (c > 0.1f) {
                float dd = sqrtf(x * x + y * y + z * z);
                s1 += (double)dd;
                s2 += (double)dd * (double)dd;
                cnt++;
                if (c >= q) {
                    mnx = fminf(mnx, x); mny = fminf(mny, y); mnz = fminf(mnz, z);
                    mxx = fmaxf(mxx, x); mxy = fmaxf(mxy, y); mxz = fmaxf(mxz, z);
                }
            }
        }
    }
    for (int o = 32; o > 0; o >>= 1) {
        mnx = fminf(mnx, __shfl_xor(mnx, o)); mny = fminf(mny, __shfl_xor(mny, o));
        mnz = fminf(mnz, __shfl_xor(mnz, o));
        mxx = fmaxf(mxx, __shfl_xor(mxx, o)); mxy = fmaxf(mxy, __shfl_xor(mxy, o));
        mxz = fmaxf(mxz, __shfl_xor(mxz, o));
        s1 += __shfl_xor(s1, o); s2 += __shfl_xor(s2, o);
        cnt += __shfl_xor(cnt, o);
    }
    __shared__ float  rf[6][4];
    __shared__ double rd[2][4];
    __shared__ uint32_t rc[4];
    int wave = threadIdx.x >> 6, lane = threadIdx.x & 63;
    if (lane == 0) {
        rf[0][wave] = mnx; rf[1][wave] = mny; rf[2][wave] = mnz;
        rf[3][wave] = mxx; rf[4][wave] = mxy; rf[5][wave] = mxz;
        rd[0][wave] = s1;  rd[1][wave] = s2;  rc[wave] = cnt;
    }
    __syncthreads();
    if (threadIdx.x == 0) {
        size_t b6 = (size_t)blockIdx.x * 6;
        pbf[b6 + 0] = fminf(fminf(rf[0][0], rf[0][1]), fminf(rf[0][2], rf[0][3]));
        pbf[b6 + 1] = fminf(fminf(rf[1][0], rf[1][1]), fminf(rf[1][2], rf[1][3]));
        pbf[b6 + 2] = fminf(fminf(rf[2][0], rf[2][1]), fminf(rf[2][2], rf[2][3]));
        pbf[b6 + 3] = fmaxf(fmaxf(rf[3][0], rf[3][1]), fmaxf(rf[3][2], rf[3][3]));
        pbf[b6 + 4] = fmaxf(fmaxf(rf[4][0], rf[4][1]), fmaxf(rf[4][2], rf[4][3]));
        pbf[b6 + 5] = fmaxf(fmaxf(rf[5][0], rf[5][1]), fmaxf(rf[5][2], rf[5][3]));
        pbd[(size_t)blockIdx.x * 2]     = rd[0][0] + rd[0][1] + rd[0][2] + rd[0][3];
        pbd[(size_t)blockIdx.x * 2 + 1] = rd[1][0] + rd[1][1] + rd[1][2] + rd[1][3];
        pbc[blockIdx.x] = rc[0] + rc[1] + rc[2] + rc[3];
    }
}

// K2b: fold 2048 block partials -> bbox + sums
__global__ __launch_bounds__(256) void k_reduce(const float* __restrict__ pbf,
                                                const double* __restrict__ pbd,
                                                const uint32_t* __restrict__ pbc,
                                                float* __restrict__ bbox,
                                                double* __restrict__ sums) {
    float mnx = 1e30f, mny = 1e30f, mnz = 1e30f;
    float mxx = -1e30f, mxy = -1e30f, mxz = -1e30f;
    double s1 = 0.0, s2 = 0.0;
    uint32_t cnt = 0;
    for (int b = threadIdx.x; b < NBLK_STATS; b += 256) {
        size_t b6 = (size_t)b * 6;
        mnx = fminf(mnx, pbf[b6 + 0]); mny = fminf(mny, pbf[b6 + 1]);
        mnz = fminf(mnz, pbf[b6 + 2]);
        mxx = fmaxf(mxx, pbf[b6 + 3]); mxy = fmaxf(mxy, pbf[b6 + 4]);
        mxz = fmaxf(mxz, pbf[b6 + 5]);
        s1 += pbd[(size_t)b * 2]; s2 += pbd[(size_t)b * 2 + 1];
        cnt += pbc[b];
    }
    for (int o = 32; o > 0; o >>= 1) {
        mnx = fminf(mnx, __shfl_xor(mnx, o)); mny = fminf(mny, __shfl_xor(mny, o));
        mnz = fminf(mnz, __shfl_xor(mnz, o));
        mxx = fmaxf(mxx, __shfl_xor(mxx, o)); mxy = fmaxf(mxy, __shfl_xor(mxy, o));
        mxz = fmaxf(mxz, __shfl_xor(mxz, o));
        s1 += __shfl_xor(s1, o); s2 += __shfl_xor(s2, o);
        cnt += __shfl_xor(cnt, o);
    }
    __shared__ float  rf[6][4];
    __shared__ double rd[2][4];
    __shared__ uint32_t rc[4];
    int wave = threadIdx.x >> 6, lane = threadIdx.x & 63;
    if (lane == 0) {
        rf[0][wave] = mnx; rf[1][wave] = mny; rf[2][wave] = mnz;
        rf[3][wave] = mxx; rf[4][wave] = mxy; rf[5][wave] = mxz;
        rd[0][wave] = s1;  rd[1][wave] = s2;  rc[wave] = cnt;
    }
    __syncthreads();
    if (threadIdx.x == 0) {
        bbox[0] = fminf(fminf(rf[0][0], rf[0][1]), fminf(rf[0][2], rf[0][3]));
        bbox[1] = fminf(fminf(rf[1][0], rf[1][1]), fminf(rf[1][2], rf[1][3]));
        bbox[2] = fminf(fminf(rf[2][0], rf[2][1]), fminf(rf[2][2], rf[2][3]));
        bbox[3] = fmaxf(fmaxf(rf[3][0], rf[3][1]), fmaxf(rf[3][2], rf[3][3]));
        bbox[4] = fmaxf(fmaxf(rf[4][0], rf[4][1]), fmaxf(rf[4][2], rf[4][3]));
        bbox[5] = fmaxf(fmaxf(rf[5][0], rf[5][1]), fmaxf(rf[5][2], rf[5][3]));
        sums[0] = rd[0][0] + rd[0][1] + rd[0][2] + rd[0][3];
        sums[1] = rd[1][0] + rd[1][1] + rd[1][2] + rd[1][3];
        sums[2] = (double)(rc[0] + rc[1] + rc[2] + rc[3]);
    }
}

// K3: fused 3-scale LDS voxel bitmaps, 8 blocks/frame, OR-merge to global
__global__ __launch_bounds__(256) void k_voxel(const float* __restrict__ pts,
                                               const float* __restrict__ conf,
                                               const float* __restrict__ med,
                                               const float* __restrict__ bbox,
                                               uint32_t* __restrict__ gbm) {
    int f = blockIdx.x >> 3;
    int chunk = blockIdx.x & 7;
    __shared__ uint32_t bm[WORDS_BM];
    for (int i = threadIdx.x; i < WORDS_BM; i += 256) bm[i] = 0;
    float pmnx = bbox[0], pmny = bbox[1], pmnz = bbox[2];
    float ex = bbox[3] - pmnx, ey = bbox[4] - pmny, ez = bbox[5] - pmnz;
    float me = fminf(ex, fminf(ey, ez));
    float i40 = 40.0f / me, i20 = 20.0f / me, i10 = 10.0f / me;
    float q = med[f];
    __syncthreads();
    const size_t base = (size_t)f * NPF + (size_t)chunk * (NPF / 8);
    const float4* c4 = (const float4*)(conf + base);
    const float4* p4 = (const float4*)(pts + base * 3);
    for (int i = threadIdx.x; i < NPF / 32; i += 256) {
        float4 cc = c4[i];
        float4 a = p4[3 * (size_t)i], b = p4[3 * (size_t)i + 1], d = p4[3 * (size_t)i + 2];
        float cv[4] = {cc.x, cc.y, cc.z, cc.w};
        float v[12] = {a.x, a.y, a.z, a.w, b.x, b.y, b.z, b.w, d.x, d.y, d.z, d.w};
        #pragma unroll
        for (int j = 0; j < 4; j++) {
            float c = cv[j];
            if (c > 0.1f && c >= q) {
                float x = v[3 * j] - pmnx, y = v[3 * j + 1] - pmny, z = v[3 * j + 2] - pmnz;
                int cx, cy, cz, bit;
                cx = (int)floorf(x * i40); cy = (int)floorf(y * i40); cz = (int)floorf(z * i40);
                cx = min(max(cx, 0), 63); cy = min(max(cy, 0), 63); cz = min(max(cz, 0), 63);
                bit = (cx << 12) | (cy << 6) | cz;
                atomicOr(&bm[bit >> 5], 1u << (bit & 31));
                cx = (int)floorf(x * i20); cy = (int)floorf(y * i20); cz = (int)floorf(z * i20);
                cx = min(max(cx, 0), 31); cy = min(max(cy, 0), 31); cz = min(max(cz, 0), 31);
                bit = (cx << 10) | (cy << 5) | cz;
                atomicOr(&bm[8192 + (bit >> 5)], 1u << (bit & 31));
                cx = (int)floorf(x * i10); cy = (int)floorf(y * i10); cz = (int)floorf(z * i10);
                cx = min(max(cx, 0), 15); cy = min(max(cy, 0), 15); cz = min(max(cz, 0), 15);
                bit = (cx << 8) | (cy << 4) | cz;
                atomicOr(&bm[9216 + (bit >> 5)], 1u << (bit & 31));
            }
        }
    }
    __syncthreads();
    uint32_t* g = gbm + (size_t)f * WORDS_BM;
    for (int i = threadIdx.x; i < WORDS_BM; i += 256) {
        uint32_t v = bm[i];
        if (v) atomicOr(&g[i], v);
    }
}

// K4: popcount per frame -> counts; block 0 finalizes complexity
__global__ __launch_bounds__(256) void k_final(const uint32_t* __restrict__ gbm,
                                               const double* __restrict__ sums,
                                               float* __restrict__ out) {
    int f = blockIdx.x;
    const uint32_t* g = gbm + (size_t)f * WORDS_BM;
    uint32_t c40 = 0, c20 = 0, c10 = 0;
    for (int i = threadIdx.x; i < 8192; i += 256) c40 += __popc(g[i]);
    for (int i = threadIdx.x; i < 1024; i += 256) c20 += __popc(g[8192 + i]);
    for (int i = threadIdx.x; i < 128; i += 256) c10 += __popc(g[9216 + i]);
    for (int o = 32; o > 0; o >>= 1) {
        c40 += __shfl_xor(c40, o);
        c20 += __shfl_xor(c20, o);
        c10 += __shfl_xor(c10, o);
    }
    __shared__ uint32_t red[3][4];
    int wave = threadIdx.x >> 6, lane = threadIdx.x & 63;
    if (lane == 0) { red[0][wave] = c40; red[1][wave] = c20; red[2][wave] = c10; }
    __syncthreads();
    if (threadIdx.x == 0) {
        uint32_t t40 = red[0][0] + red[0][1] + red[0][2] + red[0][3];
        uint32_t t20 = red[1][0] + red[1][1] + red[1][2] + red[1][3];
        uint32_t t10 = red[2][0] + red[2][1] + red[2][2] + red[2][3];
        out[0 * S_FRAMES + f] = (float)t10;
        out[1 * S_FRAMES + f] = (float)t20;
        out[2 * S_FRAMES + f] = (float)t40;
        out[3 * S_FRAMES + f] = (float)t20; // adaptive lambda == 20
        if (f == 0) {
            double n = sums[2];
            double s1 = sums[0], s2 = sums[1];
            double mean = s1 / n;
            double var = (s2 - n * mean * mean) / (n - 1.0);
            out[4 * S_FRAMES] = (float)(sqrt(var) * (n / (double)TOT));
        }
    }
}

extern "C" void kernel_launch(void* const* d_in, const int* in_sizes, int n_in,
                              void* d_out, int out_size, void* d_ws, size_t ws_size,
                              hipStream_t stream) {
    const float* pts  = (const float*)d_in[0];
    const float* conf = (const float*)d_in[1];
    float* out = (float*)d_out;
    char* ws = (char*)d_ws;
    uint32_t* hist = (uint32_t*)(ws + OFF_HIST);
    float*    med  = (float*)(ws + OFF_MED);
    float*    bbox = (float*)(ws + OFF_BBOX);
    double*   sums = (double*)(ws + OFF_SUMS);
    float*    pbf  = (float*)(ws + OFF_PBF);
    double*   pbd  = (double*)(ws + OFF_PBD);
    uint32_t* pbc  = (uint32_t*)(ws + OFF_PBC);
    uint32_t* hdr  = (uint32_t*)(ws + OFF_HDR);
    uint32_t* ccnt = (uint32_t*)(ws + OFF_CCNT);
    float*    cand = (float*)(ws + OFF_CAND);
    uint32_t* gbm  = (uint32_t*)(ws + OFF_BM);

    k_hist   <<<NBLK_HIST,    256, 0, stream>>>(conf, hist, gbm);
    k_findbin<<<S_FRAMES,     256, 0, stream>>>(hist, hdr, ccnt);
    k_collect<<<S_FRAMES * 8, 256, 0, stream>>>(conf, hdr, ccnt, cand);
    k_select <<<S_FRAMES,      64, 0, stream>>>(hdr, ccnt, cand, med);
    k_stats  <<<NBLK_STATS,   256, 0, stream>>>(pts, conf, med, pbf, pbd, pbc);
    k_reduce <<<1,            256, 0, stream>>>(pbf, pbd, pbc, bbox, sums);
    k_voxel  <<<S_FRAMES * 8, 256, 0, stream>>>(pts, conf, med, bbox, gbm);
    k_final  <<<S_FRAMES,     256, 0, stream>>>(gbm, sums, out);
}